// Round 6
// baseline (390.743 us; speedup 1.0000x reference)
//
#include <hip/hip_runtime.h>
#include <hip/hip_bf16.h>

#define L_SZ 1024
#define P_SZ 2048
#define HID 256
#define NH 8
#define HD 32
#define NRBF 50
#define CH 32
#define NCH 64

typedef unsigned int uint32;
typedef _Float16 half2_t __attribute__((ext_vector_type(2)));
typedef __fp16 fp16x2_t __attribute__((ext_vector_type(2)));

__constant__ float kINV_SCALE = 0.17677669529663687f; // 1/sqrt(32)

static __device__ __forceinline__ unsigned short f2h(float f) {
    union { _Float16 h; unsigned short u; } x; x.h = (_Float16)f; return x.u;
}
static __device__ __forceinline__ half2_t u2h2(uint32 u) {
    union { uint32 u; half2_t h; } x; x.u = u; return x.h;
}
static __device__ __forceinline__ half2_t pk2h(float a, float b) {
    union { fp16x2_t p; half2_t h; } x; x.p = __builtin_amdgcn_cvt_pkrtz(a, b); return x.h;
}

// async global->LDS, 16B per lane. LDS dest = uniform base + lane*16.
static __device__ __forceinline__ void g2l16(const void* g, void* l) {
    __builtin_amdgcn_global_load_lds(
        (__attribute__((address_space(1))) void*)(void*)g,
        (__attribute__((address_space(3))) void*)l, 16, 0, 0);
}
static __device__ __forceinline__ void g2l4(const void* g, void* l) {
    __builtin_amdgcn_global_load_lds(
        (__attribute__((address_space(1))) void*)(void*)g,
        (__attribute__((address_space(3))) void*)l, 4, 0, 0);
}

// ---------------------------------------------------------------------------
// Kernel 1: Q = lig@Wq+bq (f32), K = prot@Wk+bk (f16), V = prot@Wv+bv (f16)
// ---------------------------------------------------------------------------
__global__ __launch_bounds__(64) void k_proj(
    const float* __restrict__ lig, const float* __restrict__ prot,
    const float* __restrict__ Wq, const float* __restrict__ bq,
    const float* __restrict__ Wk, const float* __restrict__ bk,
    const float* __restrict__ Wv, const float* __restrict__ bv,
    float* __restrict__ Qf, unsigned short* __restrict__ Kb,
    unsigned short* __restrict__ Vb)
{
    __shared__ float As[8 * HID];
    const int t = threadIdx.x;
    const int r0 = blockIdx.x * 8;

    const float* src; const float* W; const float* bias; int mode; int row0;
    if (r0 < L_SZ)            { src = lig  + (size_t)r0 * HID;               W = Wq; bias = bq; mode = 0; row0 = r0; }
    else if (r0 < L_SZ + P_SZ){ src = prot + (size_t)(r0 - L_SZ) * HID;      W = Wk; bias = bk; mode = 1; row0 = r0 - L_SZ; }
    else                      { src = prot + (size_t)(r0 - L_SZ - P_SZ)*HID; W = Wv; bias = bv; mode = 2; row0 = r0 - L_SZ - P_SZ; }

    float4* A4 = (float4*)As;
    const float4* S4 = (const float4*)src;
    #pragma unroll
    for (int j = 0; j < 8; ++j) A4[t + j * 64] = S4[t + j * 64];
    __syncthreads();

    float acc[8][4];
    #pragma unroll
    for (int r = 0; r < 8; ++r)
        #pragma unroll
        for (int c = 0; c < 4; ++c) acc[r][c] = 0.f;

    for (int k4 = 0; k4 < 64; ++k4) {
        float4 av[8];
        #pragma unroll
        for (int r = 0; r < 8; ++r) av[r] = A4[r * 64 + k4];
        #pragma unroll
        for (int kk = 0; kk < 4; ++kk) {
            const float* wr = W + (size_t)(k4 * 4 + kk) * HID + t;
            #pragma unroll
            for (int c = 0; c < 4; ++c) {
                float wv = wr[c * 64];
                #pragma unroll
                for (int r = 0; r < 8; ++r)
                    acc[r][c] += ((const float*)&av[r])[kk] * wv;
            }
        }
    }

    #pragma unroll
    for (int c = 0; c < 4; ++c) {
        const int col = t + c * 64;
        const float bb = bias[col];
        #pragma unroll
        for (int r = 0; r < 8; ++r) {
            float v = acc[r][c] + bb;
            size_t idx = (size_t)(row0 + r) * HID + col;
            if (mode == 0)      Qf[idx] = v;
            else if (mode == 1) Kb[idx] = f2h(v);
            else                Vb[idx] = f2h(v);
        }
    }
}

// ---------------------------------------------------------------------------
// Kernel 2: fused bias + QK^T + online softmax + normalize + PV.
// One block per ligand row, 256 threads, 3 blocks/CU (LDS 44.9 KB).
// Raw logits stream f32 to attn_out (global, L2-hot); stats held online in
// registers; normalize pass rewrites attn_out in place; PV reads weights
// from L2 and V from double-buffered LDS.
// LDS: kv dbuf 2x16384 | rbf dbuf 2x6400 @32768 | red[16] @45568.
// ---------------------------------------------------------------------------
__global__ __launch_bounds__(256, 3) void k_attn(
    const float* __restrict__ rbf, const float* __restrict__ Qf,
    const unsigned short* __restrict__ Kb, const unsigned short* __restrict__ Vb,
    const float* __restrict__ Wrbf, const float* __restrict__ brbf,
    float* __restrict__ attn_out, float* __restrict__ att_ws)
{
    __shared__ __align__(16) char sm[45632];
    float* red = (float*)(sm + 45568);

    const int t = threadIdx.x;
    const int lane = t & 63;
    const int wv = t >> 6;
    const int r = t & 31;     // protein row within chunk
    const int h = t >> 5;     // head 0..7
    const int l = blockIdx.x;
    float* aoL = attn_out + (size_t)l * (P_SZ * NH);

    // stage one 32-row K or V chunk (16 KB), XOR-swizzled via pre-swizzled
    // global source (LDS dest stays linear per global_load_lds semantics)
    auto stageKV = [&](const unsigned short* src, int c, char* dst) {
        const char* gb = (const char*)src + (size_t)c * (CH * 512);
        #pragma unroll
        for (int k = 0; k < 4; ++k) {
            int s = wv * 4 + k;               // 1KB slab 0..15
            int row = s * 2 + (lane >> 5);
            int off = ((lane & 31) ^ (row & 31)) << 4;
            g2l16(gb + row * 512 + off, dst + s * 1024);
        }
    };
    // stage one 32-row rbf chunk (6400 B), linear
    auto stageRBF = [&](int c, char* dst) {
        const char* gb = (const char*)rbf + (size_t)l * 409600 + (size_t)c * 6400;
        g2l16(gb + wv * 1024 + (lane << 4), dst + wv * 1024);
        if (wv == 0)      g2l16(gb + 4096 + (lane << 4), dst + 4096);
        else if (wv == 1) g2l16(gb + 5120 + (lane << 4), dst + 5120);
        else if (wv == 2) g2l4 (gb + 6144 + (lane << 2), dst + 6144);
    };

    // ---- per-thread preloads: Wrbf column h (25 half2), Q head h (16 half2)
    half2_t wrb[25];
    #pragma unroll
    for (int j = 0; j < 25; ++j)
        wrb[j] = pk2h(Wrbf[(2 * j) * NH + h], Wrbf[(2 * j + 1) * NH + h]);
    const float bh = brbf[h];

    half2_t qp[16];
    {
        const float* qq = Qf + (size_t)l * HID + h * HD;
        #pragma unroll
        for (int n = 0; n < 16; ++n)
            qp[n] = pk2h(qq[2 * n], qq[2 * n + 1]);
    }

    // ================= Pass 1: logits + online (m,s) ========================
    stageKV(Kb, 0, sm);
    stageRBF(0, sm + 32768);
    asm volatile("s_waitcnt vmcnt(0)" ::: "memory");
    __syncthreads();

    float mx = -3.0e38f, sme = 0.f;
    for (int c = 0; c < NCH; ++c) {
        const int cb = c & 1;
        char* kb = sm + cb * 16384;
        char* rb = sm + 32768 + cb * 6400;
        if (c + 1 < NCH) {                       // async prefetch next chunk
            stageKV(Kb, c + 1, sm + (cb ^ 1) * 16384);
            stageRBF(c + 1, sm + 32768 + (cb ^ 1) * 6400);
        }
        // bias = brbf[h] + rbf[l, p, :] . Wrbf[:, h]
        float bias = bh;
        const char* rrow = rb + r * 200;
        #pragma unroll
        for (int j = 0; j < 25; ++j) {
            float2 v = *(const float2*)(rrow + j * 8);
            bias = __builtin_amdgcn_fdot2(pk2h(v.x, v.y), wrb[j], bias, false);
        }
        // qk = Q[l,h,:] . K[p,h,:]
        float qk = 0.f;
        const char* krow = kb + r * 512;
        #pragma unroll
        for (int jw = 0; jw < 4; ++jw) {
            int off = (h * 64 + jw * 16) ^ (r << 4);
            uint4 kk = *(const uint4*)(krow + off);
            qk = __builtin_amdgcn_fdot2(u2h2(kk.x), qp[jw * 4 + 0], qk, false);
            qk = __builtin_amdgcn_fdot2(u2h2(kk.y), qp[jw * 4 + 1], qk, false);
            qk = __builtin_amdgcn_fdot2(u2h2(kk.z), qp[jw * 4 + 2], qk, false);
            qk = __builtin_amdgcn_fdot2(u2h2(kk.w), qp[jw * 4 + 3], qk, false);
        }
        float lg = qk * kINV_SCALE + bias;
        // online max/sum
        float nm = fmaxf(mx, lg);
        sme = sme * __expf(mx - nm) + __expf(lg - nm);
        mx = nm;
        // stream raw logit to global (block writes 1KB contiguous per chunk)
        aoL[(c * CH + r) * NH + h] = lg;

        asm volatile("s_waitcnt vmcnt(0)" ::: "memory");
        __syncthreads();
    }

    // ---- merge (m,s) across the 32 lanes owning head h ----
    #pragma unroll
    for (int msk = 1; msk <= 16; msk <<= 1) {
        float om = __shfl_xor(mx, msk);
        float os = __shfl_xor(sme, msk);
        float nm = fmaxf(mx, om);
        sme = sme * __expf(mx - nm) + os * __expf(om - nm);
        mx = nm;
    }
    if ((t & 31) == 0) { red[h * 2] = mx; red[h * 2 + 1] = 1.f / sme; }

    stageKV(Vb, 0, sm);          // overlap V chunk-0 stage with pass 2
    __syncthreads();

    // ================= Pass 2: normalize attn_out in place ==================
    {
        const int h2 = t & 7;                     // f&7 is constant per thread
        const float m = red[h2 * 2];
        const float inv = red[h2 * 2 + 1];
        #pragma unroll 4
        for (int n = 0; n < 64; ++n) {
            int f = t + n * 256;
            float w = __expf(aoL[f] - m) * inv;
            aoL[f] = w;
        }
    }
    asm volatile("s_waitcnt vmcnt(0)" ::: "memory");
    __syncthreads();

    // ================= Pass 3: PV (weights from L2, V from LDS) =============
    {
        const int h3 = t >> 5;        // head
        const int dq = (t >> 3) & 3;  // dim quad (8 dims)
        const int ps = t & 7;         // p slice
        const int vinner = h3 * 64 + dq * 16;
        float acc[8] = {0.f, 0.f, 0.f, 0.f, 0.f, 0.f, 0.f, 0.f};
        for (int c = 0; c < NCH; ++c) {
            const int cb = c & 1;
            char* vb = sm + cb * 16384;
            if (c + 1 < NCH) stageKV(Vb, c + 1, sm + (cb ^ 1) * 16384);
            #pragma unroll
            for (int m = 0; m < 4; ++m) {
                int rr = m * 8 + ps;
                float w = aoL[(c * CH + rr) * NH + h3];
                int off = vinner ^ (rr << 4);
                uint4 vvv = *(const uint4*)(vb + rr * 512 + off);
                half2_t x0 = u2h2(vvv.x), x1 = u2h2(vvv.y), x2 = u2h2(vvv.z), x3 = u2h2(vvv.w);
                acc[0] += w * (float)x0.x; acc[1] += w * (float)x0.y;
                acc[2] += w * (float)x1.x; acc[3] += w * (float)x1.y;
                acc[4] += w * (float)x2.x; acc[5] += w * (float)x2.y;
                acc[6] += w * (float)x3.x; acc[7] += w * (float)x3.y;
            }
            asm volatile("s_waitcnt vmcnt(0)" ::: "memory");
            __syncthreads();
        }
        #pragma unroll
        for (int d = 0; d < 8; ++d) {
            acc[d] += __shfl_xor(acc[d], 1);
            acc[d] += __shfl_xor(acc[d], 2);
            acc[d] += __shfl_xor(acc[d], 4);
        }
        if (ps == 0) {
            float* dst = att_ws + (size_t)l * HID + h3 * HD + dq * 8;
            *(float4*)dst       = make_float4(acc[0], acc[1], acc[2], acc[3]);
            *(float4*)(dst + 4) = make_float4(acc[4], acc[5], acc[6], acc[7]);
        }
    }
}

// ---------------------------------------------------------------------------
// Kernel 3: y = lig + attended@Wo + bo; LayerNorm
// ---------------------------------------------------------------------------
__global__ __launch_bounds__(256) void k_out(
    const float* __restrict__ att, const float* __restrict__ lig,
    const float* __restrict__ Wo, const float* __restrict__ bo,
    const float* __restrict__ gamma, const float* __restrict__ beta,
    float* __restrict__ out)
{
    __shared__ float a[HID];
    __shared__ float red[8];
    const int l = blockIdx.x, t = threadIdx.x;
    if (t < 64) ((float4*)a)[t] = ((const float4*)(att + (size_t)l * HID))[t];
    __syncthreads();

    float acc = bo[t];
    for (int k4 = 0; k4 < 64; ++k4) {
        float4 av = ((float4*)a)[k4];
        const float* wr = Wo + (size_t)(k4 * 4) * HID + t;
        acc += av.x * wr[0];
        acc += av.y * wr[HID];
        acc += av.z * wr[2 * HID];
        acc += av.w * wr[3 * HID];
    }
    float y = lig[(size_t)l * HID + t] + acc;

    float s = y, sq = y * y;
    #pragma unroll
    for (int msk = 1; msk < 64; msk <<= 1) {
        s  += __shfl_xor(s, msk);
        sq += __shfl_xor(sq, msk);
    }
    const int lane = t & 63, wvi = t >> 6;
    if (lane == 0) { red[wvi * 2] = s; red[wvi * 2 + 1] = sq; }
    __syncthreads();
    float ts = red[0] + red[2] + red[4] + red[6];
    float tq = red[1] + red[3] + red[5] + red[7];
    float mu = ts * (1.0f / HID);
    float var = tq * (1.0f / HID) - mu * mu;
    out[(size_t)l * HID + t] = (y - mu) * rsqrtf(var + 1e-5f) * gamma[t] + beta[t];
}

// ---------------------------------------------------------------------------
extern "C" void kernel_launch(void* const* d_in, const int* in_sizes, int n_in,
                              void* d_out, int out_size, void* d_ws, size_t ws_size,
                              hipStream_t stream)
{
    (void)in_sizes; (void)n_in; (void)out_size; (void)ws_size;

    const float* lig   = (const float*)d_in[0];
    const float* prot  = (const float*)d_in[1];
    const float* rbf   = (const float*)d_in[2];
    const float* Wq    = (const float*)d_in[5];
    const float* bq    = (const float*)d_in[6];
    const float* Wk    = (const float*)d_in[7];
    const float* bk    = (const float*)d_in[8];
    const float* Wv    = (const float*)d_in[9];
    const float* bv    = (const float*)d_in[10];
    const float* Wrbf  = (const float*)d_in[11];
    const float* brbf  = (const float*)d_in[12];
    const float* Wo    = (const float*)d_in[13];
    const float* bo    = (const float*)d_in[14];
    const float* gamma = (const float*)d_in[15];
    const float* beta  = (const float*)d_in[16];

    float* out0 = (float*)d_out;                          // [1024,256]
    float* attn = (float*)d_out + (size_t)L_SZ * HID;     // [1024,2048,8]

    char* ws = (char*)d_ws;
    float*          Qf     = (float*)ws;                          // 1 MB
    unsigned short* Kb     = (unsigned short*)(ws + (1u << 20));  // 1 MB
    unsigned short* Vb     = (unsigned short*)(ws + (2u << 20));  // 1 MB
    float*          att_ws = (float*)(ws + (3u << 20));           // 1 MB

    hipLaunchKernelGGL(k_proj, dim3((L_SZ + 2 * P_SZ) / 8), dim3(64), 0, stream,
                       lig, prot, Wq, bq, Wk, bk, Wv, bv, Qf, Kb, Vb);
    hipLaunchKernelGGL(k_attn, dim3(L_SZ), dim3(256), 0, stream,
                       rbf, Qf, Kb, Vb, Wrbf, brbf, attn, att_ws);
    hipLaunchKernelGGL(k_out, dim3(L_SZ), dim3(256), 0, stream,
                       att_ws, lig, Wo, bo, gamma, beta, out0);
}

// Round 7
// 336.581 us; speedup vs baseline: 1.1609x; 1.1609x over previous
//
#include <hip/hip_runtime.h>
#include <hip/hip_bf16.h>

#define L_SZ 1024
#define P_SZ 2048
#define HID 256
#define NH 8
#define HD 32
#define NRBF 50
#define CH 32
#define NCH 64
#define RBF_BYTES ((size_t)L_SZ * P_SZ * NRBF * 4)

typedef unsigned int uint32;
typedef _Float16 half2_t __attribute__((ext_vector_type(2)));
typedef __fp16 fp16x2_t __attribute__((ext_vector_type(2)));

__constant__ float kINV_SCALE = 0.17677669529663687f; // 1/sqrt(32)

static __device__ __forceinline__ unsigned short f2h(float f) {
    union { _Float16 h; unsigned short u; } x; x.h = (_Float16)f; return x.u;
}
static __device__ __forceinline__ float h2f(unsigned short u) {
    union { unsigned short u; _Float16 h; } x; x.u = u; return (float)x.h;
}
static __device__ __forceinline__ half2_t u2h2(uint32 u) {
    union { uint32 u; half2_t h; } x; x.u = u; return x.h;
}
static __device__ __forceinline__ half2_t pk2h(float a, float b) {
    union { fp16x2_t p; half2_t h; } x; x.p = __builtin_amdgcn_cvt_pkrtz(a, b); return x.h;
}

// async global->LDS, 16B per lane. LDS dest = wave-uniform base + lane*16.
static __device__ __forceinline__ void g2l16(const void* g, void* l) {
    __builtin_amdgcn_global_load_lds(
        (__attribute__((address_space(1))) void*)(void*)g,
        (__attribute__((address_space(3))) void*)l, 16, 0, 0);
}

#define WAITV(n) asm volatile("s_waitcnt vmcnt(" #n ")" ::: "memory")
#define WAITLGKM asm volatile("s_waitcnt lgkmcnt(0)" ::: "memory")

// ---------------------------------------------------------------------------
// Kernel 1: Q = lig@Wq+bq (f32), K = prot@Wk+bk (f16), V = prot@Wv+bv (f16)
// ---------------------------------------------------------------------------
__global__ __launch_bounds__(64) void k_proj(
    const float* __restrict__ lig, const float* __restrict__ prot,
    const float* __restrict__ Wq, const float* __restrict__ bq,
    const float* __restrict__ Wk, const float* __restrict__ bk,
    const float* __restrict__ Wv, const float* __restrict__ bv,
    float* __restrict__ Qf, unsigned short* __restrict__ Kb,
    unsigned short* __restrict__ Vb)
{
    __shared__ float As[8 * HID];
    const int t = threadIdx.x;
    const int r0 = blockIdx.x * 8;

    const float* src; const float* W; const float* bias; int mode; int row0;
    if (r0 < L_SZ)            { src = lig  + (size_t)r0 * HID;               W = Wq; bias = bq; mode = 0; row0 = r0; }
    else if (r0 < L_SZ + P_SZ){ src = prot + (size_t)(r0 - L_SZ) * HID;      W = Wk; bias = bk; mode = 1; row0 = r0 - L_SZ; }
    else                      { src = prot + (size_t)(r0 - L_SZ - P_SZ)*HID; W = Wv; bias = bv; mode = 2; row0 = r0 - L_SZ - P_SZ; }

    float4* A4 = (float4*)As;
    const float4* S4 = (const float4*)src;
    #pragma unroll
    for (int j = 0; j < 8; ++j) A4[t + j * 64] = S4[t + j * 64];
    __syncthreads();

    float acc[8][4];
    #pragma unroll
    for (int r = 0; r < 8; ++r)
        #pragma unroll
        for (int c = 0; c < 4; ++c) acc[r][c] = 0.f;

    for (int k4 = 0; k4 < 64; ++k4) {
        float4 av[8];
        #pragma unroll
        for (int r = 0; r < 8; ++r) av[r] = A4[r * 64 + k4];
        #pragma unroll
        for (int kk = 0; kk < 4; ++kk) {
            const float* wr = W + (size_t)(k4 * 4 + kk) * HID + t;
            #pragma unroll
            for (int c = 0; c < 4; ++c) {
                float wv = wr[c * 64];
                #pragma unroll
                for (int r = 0; r < 8; ++r)
                    acc[r][c] += ((const float*)&av[r])[kk] * wv;
            }
        }
    }

    #pragma unroll
    for (int c = 0; c < 4; ++c) {
        const int col = t + c * 64;
        const float bb = bias[col];
        #pragma unroll
        for (int r = 0; r < 8; ++r) {
            float v = acc[r][c] + bb;
            size_t idx = (size_t)(row0 + r) * HID + col;
            if (mode == 0)      Qf[idx] = v;
            else if (mode == 1) Kb[idx] = f2h(v);
            else                Vb[idx] = f2h(v);
        }
    }
}

// ---------------------------------------------------------------------------
// Kernel 2: fused bias + QK^T + softmax + weights + PV.
// One block per ligand row, 256 threads, 2 blocks/CU.
// T4 counted-vmcnt pipeline: stage(c+1) stays in flight across the raw
// s_barrier; iter end waits vmcnt(6) (pass1) / vmcnt(4) (pass3) — never 0
// inside the loops. Raw __builtin_amdgcn_s_barrier avoids the compiler's
// vmcnt(0) drain that __syncthreads would emit.
// LDS (81920 B = 80 KiB, 2 blocks/CU):
//   kv dbuf 2x16384 @0 | rbf dbuf 2x8192 @32768 (2048B wave regions,
//   8 rows x 200B each + pad) | slg f16 [2048][8] swizzled @49152 |
//   red[16] overlaid @32768 after pass1.
// ---------------------------------------------------------------------------
__global__ __launch_bounds__(256, 2) void k_attn(
    const float* __restrict__ rbf, const float* __restrict__ Qf,
    const unsigned short* __restrict__ Kb, const unsigned short* __restrict__ Vb,
    const float* __restrict__ Wrbf, const float* __restrict__ brbf,
    float* __restrict__ attn_out, float* __restrict__ att_ws)
{
    __shared__ __align__(16) char sm[81920];
    char* rbfB = sm + 32768;
    char* slgB = sm + 49152;
    float* red = (float*)(sm + 32768);   // overlaid on rbf area (dead after pass1)

    const int t = threadIdx.x;
    const int lane = t & 63;
    const int wv = t >> 6;
    const int r = t & 31;     // protein row within chunk
    const int h = t >> 5;     // head 0..7
    const int l = blockIdx.x;

    // stage one 32-row K or V chunk (16 KB), XOR-swizzled via pre-swizzled
    // global source (LDS dest stays linear). 4 loads per wave.
    auto stageKV = [&](const unsigned short* src, int c, char* dst) {
        const char* gb = (const char*)src + (size_t)c * (CH * 512);
        #pragma unroll
        for (int k = 0; k < 4; ++k) {
            int s = wv * 4 + k;               // 1KB slab 0..15
            int row = s * 2 + (lane >> 5);
            int off = ((lane & 31) ^ (row & 31)) << 4;
            g2l16(gb + row * 512 + off, dst + s * 1024);
        }
    };
    // stage one 32-row rbf chunk (6400 B) into 4x2048B wave regions.
    // 2 loads per wave, uniform. Rows land at (r>>3)*2048 + (r&7)*200.
    auto stageRBF = [&](int c, char* dst) {
        size_t base = (size_t)l * 409600 + (size_t)c * 6400;
        size_t o1 = base + (size_t)(wv * 1600 + (lane << 4));
        g2l16((const char*)rbf + o1, dst + wv * 2048);
        size_t o2 = base + (size_t)(wv * 1600 + 1024 + (lane << 4));
        if (o2 > RBF_BYTES - 16) o2 = RBF_BYTES - 16;   // tail clamp (pad lanes)
        g2l16((const char*)rbf + o2, dst + wv * 2048 + 1024);
    };

    // ---- per-thread preloads: Wrbf column h (25 half2), Q head h (16 half2)
    half2_t wrb[25];
    #pragma unroll
    for (int j = 0; j < 25; ++j)
        wrb[j] = pk2h(Wrbf[(2 * j) * NH + h], Wrbf[(2 * j + 1) * NH + h]);
    const float bh = brbf[h];

    half2_t qp[16];
    {
        const float* qq = Qf + (size_t)l * HID + h * HD;
        #pragma unroll
        for (int n = 0; n < 16; ++n)
            qp[n] = pk2h(qq[2 * n], qq[2 * n + 1]);
    }

    // slg address swizzle: dword d of row p stored at d ^ ((p>>3)&3).
    const int doff = ((((h >> 1) ^ ((r >> 3) & 3)) << 2) | ((h & 1) << 1));
    const int rbase = (r >> 3) * 2048 + (r & 7) * 200;

    // ================= Pass 1: logits + running max =========================
    stageKV(Kb, 0, sm);
    stageRBF(0, rbfB);
    WAITV(0);
    __builtin_amdgcn_s_barrier();

    float mx = -3.0e38f;
    for (int c = 0; c < NCH; ++c) {
        const int cb = c & 1;
        char* kb = sm + cb * 16384;
        char* rb = rbfB + cb * 8192;
        if (c + 1 < NCH) {                       // async prefetch next chunk
            stageKV(Kb, c + 1, sm + (cb ^ 1) * 16384);
            stageRBF(c + 1, rbfB + (cb ^ 1) * 8192);
        }
        // bias = brbf[h] + rbf[l, p, :] . Wrbf[:, h]   (dual chains)
        float b0 = bh, b1 = 0.f;
        const char* rrow = rb + rbase;
        #pragma unroll
        for (int j = 0; j < 12; ++j) {
            float2 v0 = *(const float2*)(rrow + (2 * j) * 8);
            float2 v1 = *(const float2*)(rrow + (2 * j + 1) * 8);
            b0 = __builtin_amdgcn_fdot2(pk2h(v0.x, v0.y), wrb[2 * j], b0, false);
            b1 = __builtin_amdgcn_fdot2(pk2h(v1.x, v1.y), wrb[2 * j + 1], b1, false);
        }
        {
            float2 v = *(const float2*)(rrow + 24 * 8);
            b0 = __builtin_amdgcn_fdot2(pk2h(v.x, v.y), wrb[24], b0, false);
        }
        // qk = Q[l,h,:] . K[p,h,:]   (dual chains)
        float qk0 = 0.f, qk1 = 0.f;
        const char* krow = kb + r * 512;
        #pragma unroll
        for (int jw = 0; jw < 2; ++jw) {
            int offA = (h * 64 + jw * 16) ^ (r << 4);
            int offB = (h * 64 + (jw + 2) * 16) ^ (r << 4);
            uint4 ka = *(const uint4*)(krow + offA);
            uint4 kbv = *(const uint4*)(krow + offB);
            qk0 = __builtin_amdgcn_fdot2(u2h2(ka.x),  qp[jw * 4 + 0], qk0, false);
            qk1 = __builtin_amdgcn_fdot2(u2h2(kbv.x), qp[(jw + 2) * 4 + 0], qk1, false);
            qk0 = __builtin_amdgcn_fdot2(u2h2(ka.y),  qp[jw * 4 + 1], qk0, false);
            qk1 = __builtin_amdgcn_fdot2(u2h2(kbv.y), qp[(jw + 2) * 4 + 1], qk1, false);
            qk0 = __builtin_amdgcn_fdot2(u2h2(ka.z),  qp[jw * 4 + 2], qk0, false);
            qk1 = __builtin_amdgcn_fdot2(u2h2(kbv.z), qp[(jw + 2) * 4 + 2], qk1, false);
            qk0 = __builtin_amdgcn_fdot2(u2h2(ka.w),  qp[jw * 4 + 3], qk0, false);
            qk1 = __builtin_amdgcn_fdot2(u2h2(kbv.w), qp[(jw + 2) * 4 + 3], qk1, false);
        }
        float lg = (qk0 + qk1) * kINV_SCALE + (b0 + b1);
        mx = fmaxf(mx, lg);
        *(unsigned short*)(slgB + (size_t)((c * CH + r) * 16) + doff) = f2h(lg);

        WAITV(6);                    // allow stage(c+1)'s 6 loads to stay in flight
        __builtin_amdgcn_s_barrier();
    }

    // ---- softmax stats: half-wave butterflies (32 lanes own head h) ----
    #pragma unroll
    for (int msk = 1; msk <= 16; msk <<= 1) mx = fmaxf(mx, __shfl_xor(mx, msk));
    float sme = 0.f;
    for (int c = 0; c < NCH; ++c) {
        unsigned short u = *(const unsigned short*)(slgB + (size_t)((c * CH + r) * 16) + doff);
        sme += __expf(h2f(u) - mx);
    }
    #pragma unroll
    for (int msk = 1; msk <= 16; msk <<= 1) sme += __shfl_xor(sme, msk);
    if ((t & 31) == 0) { red[h * 2] = mx; red[h * 2 + 1] = 1.f / sme; }

    __syncthreads();                 // pass boundary: full drain is fine here

    stageKV(Vb, 0, sm);              // V chunk 0 overlaps pass-2 compute

    // ================= Pass 2: normalized weights ===========================
    {
        float mh[8], ih[8];
        #pragma unroll
        for (int hh = 0; hh < 8; ++hh) { mh[hh] = red[hh * 2]; ih[hh] = red[hh * 2 + 1]; }
        const int sel = t & 1;                       // 0: heads 0-3, 1: heads 4-7
        float m0 = sel ? mh[4] : mh[0], i0 = sel ? ih[4] : ih[0];
        float m1 = sel ? mh[5] : mh[1], i1 = sel ? ih[5] : ih[1];
        float m2 = sel ? mh[6] : mh[2], i2 = sel ? ih[6] : ih[2];
        float m3 = sel ? mh[7] : mh[3], i3 = sel ? ih[7] : ih[3];
        const int x = (t >> 4) & 3;                  // (p>>3)&3, const per thread
        const int dA = (((2 * sel)     ^ x) << 2);
        const int dB = (((2 * sel + 1) ^ x) << 2);
        float4* ao = (float4*)(attn_out + (size_t)l * (P_SZ * NH));
        #pragma unroll
        for (int n = 0; n < 16; ++n) {
            int f = t + n * 256;
            int p = (t >> 1) + n * 128;
            char* rowp = slgB + p * 16;
            uint32 a = *(uint32*)(rowp + dA);
            uint32 b = *(uint32*)(rowp + dB);
            float w0 = __expf(h2f((unsigned short)(a & 0xffffu)) - m0) * i0;
            float w1 = __expf(h2f((unsigned short)(a >> 16))     - m1) * i1;
            float w2 = __expf(h2f((unsigned short)(b & 0xffffu)) - m2) * i2;
            float w3 = __expf(h2f((unsigned short)(b >> 16))     - m3) * i3;
            ao[f] = make_float4(w0, w1, w2, w3);
            *(uint32*)(rowp + dA) = (uint32)f2h(w0) | ((uint32)f2h(w1) << 16);
            *(uint32*)(rowp + dB) = (uint32)f2h(w2) | ((uint32)f2h(w3) << 16);
        }
    }
    WAITLGKM;
    WAITV(0);                        // V chunk 0 arrived during pass 2; stores drained
    __builtin_amdgcn_s_barrier();

    // ================= Pass 3: PV with double-buffered V =====================
    {
        const int h3 = t >> 5;        // head
        const int dq = (t >> 3) & 3;  // dim quad (8 dims)
        const int ps = t & 7;         // p slice
        const int vinner = h3 * 64 + dq * 16;
        float acc[8] = {0.f, 0.f, 0.f, 0.f, 0.f, 0.f, 0.f, 0.f};
        for (int c = 0; c < NCH; ++c) {
            const int cb = c & 1;
            char* vb = sm + cb * 16384;
            if (c + 1 < NCH) stageKV(Vb, c + 1, sm + (cb ^ 1) * 16384);
            #pragma unroll
            for (int m = 0; m < 4; ++m) {
                int rr = m * 8 + ps;
                int p = c * CH + rr;
                int dw = (((h3 >> 1) ^ m) << 2) | ((h3 & 1) << 1);
                float w = h2f(*(const unsigned short*)(slgB + p * 16 + dw));
                int off = vinner ^ (rr << 4);
                uint4 vvv = *(const uint4*)(vb + rr * 512 + off);
                half2_t x0 = u2h2(vvv.x), x1 = u2h2(vvv.y), x2 = u2h2(vvv.z), x3 = u2h2(vvv.w);
                acc[0] += w * (float)x0.x; acc[1] += w * (float)x0.y;
                acc[2] += w * (float)x1.x; acc[3] += w * (float)x1.y;
                acc[4] += w * (float)x2.x; acc[5] += w * (float)x2.y;
                acc[6] += w * (float)x3.x; acc[7] += w * (float)x3.y;
            }
            WAITV(4);                // allow stage(c+1)'s 4 loads to stay in flight
            __builtin_amdgcn_s_barrier();
        }
        #pragma unroll
        for (int d = 0; d < 8; ++d) {
            acc[d] += __shfl_xor(acc[d], 1);
            acc[d] += __shfl_xor(acc[d], 2);
            acc[d] += __shfl_xor(acc[d], 4);
        }
        if (ps == 0) {
            float* dst = att_ws + (size_t)l * HID + h3 * HD + dq * 8;
            *(float4*)dst       = make_float4(acc[0], acc[1], acc[2], acc[3]);
            *(float4*)(dst + 4) = make_float4(acc[4], acc[5], acc[6], acc[7]);
        }
    }
}

// ---------------------------------------------------------------------------
// Kernel 3: y = lig + attended@Wo + bo; LayerNorm
// ---------------------------------------------------------------------------
__global__ __launch_bounds__(256) void k_out(
    const float* __restrict__ att, const float* __restrict__ lig,
    const float* __restrict__ Wo, const float* __restrict__ bo,
    const float* __restrict__ gamma, const float* __restrict__ beta,
    float* __restrict__ out)
{
    __shared__ float a[HID];
    __shared__ float red[8];
    const int l = blockIdx.x, t = threadIdx.x;
    if (t < 64) ((float4*)a)[t] = ((const float4*)(att + (size_t)l * HID))[t];
    __syncthreads();

    float acc = bo[t];
    for (int k4 = 0; k4 < 64; ++k4) {
        float4 av = ((float4*)a)[k4];
        const float* wr = Wo + (size_t)(k4 * 4) * HID + t;
        acc += av.x * wr[0];
        acc += av.y * wr[HID];
        acc += av.z * wr[2 * HID];
        acc += av.w * wr[3 * HID];
    }
    float y = lig[(size_t)l * HID + t] + acc;

    float s = y, sq = y * y;
    #pragma unroll
    for (int msk = 1; msk < 64; msk <<= 1) {
        s  += __shfl_xor(s, msk);
        sq += __shfl_xor(sq, msk);
    }
    const int lane = t & 63, wvi = t >> 6;
    if (lane == 0) { red[wvi * 2] = s; red[wvi * 2 + 1] = sq; }
    __syncthreads();
    float ts = red[0] + red[2] + red[4] + red[6];
    float tq = red[1] + red[3] + red[5] + red[7];
    float mu = ts * (1.0f / HID);
    float var = tq * (1.0f / HID) - mu * mu;
    out[(size_t)l * HID + t] = (y - mu) * rsqrtf(var + 1e-5f) * gamma[t] + beta[t];
}

// ---------------------------------------------------------------------------
extern "C" void kernel_launch(void* const* d_in, const int* in_sizes, int n_in,
                              void* d_out, int out_size, void* d_ws, size_t ws_size,
                              hipStream_t stream)
{
    (void)in_sizes; (void)n_in; (void)out_size; (void)ws_size;

    const float* lig   = (const float*)d_in[0];
    const float* prot  = (const float*)d_in[1];
    const float* rbf   = (const float*)d_in[2];
    const float* Wq    = (const float*)d_in[5];
    const float* bq    = (const float*)d_in[6];
    const float* Wk    = (const float*)d_in[7];
    const float* bk    = (const float*)d_in[8];
    const float* Wv    = (const float*)d_in[9];
    const float* bv    = (const float*)d_in[10];
    const float* Wrbf  = (const float*)d_in[11];
    const float* brbf  = (const float*)d_in[12];
    const float* Wo    = (const float*)d_in[13];
    const float* bo    = (const float*)d_in[14];
    const float* gamma = (const float*)d_in[15];
    const float* beta  = (const float*)d_in[16];

    float* out0 = (float*)d_out;                          // [1024,256]
    float* attn = (float*)d_out + (size_t)L_SZ * HID;     // [1024,2048,8]

    char* ws = (char*)d_ws;
    float*          Qf     = (float*)ws;                          // 1 MB
    unsigned short* Kb     = (unsigned short*)(ws + (1u << 20));  // 1 MB
    unsigned short* Vb     = (unsigned short*)(ws + (2u << 20));  // 1 MB
    float*          att_ws = (float*)(ws + (3u << 20));           // 1 MB

    hipLaunchKernelGGL(k_proj, dim3((L_SZ + 2 * P_SZ) / 8), dim3(64), 0, stream,
                       lig, prot, Wq, bq, Wk, bk, Wv, bv, Qf, Kb, Vb);
    hipLaunchKernelGGL(k_attn, dim3(L_SZ), dim3(256), 0, stream,
                       rbf, Qf, Kb, Vb, Wrbf, brbf, attn, att_ws);
    hipLaunchKernelGGL(k_out, dim3(L_SZ), dim3(256), 0, stream,
                       att_ws, lig, Wo, bo, gamma, beta, out0);
}

// Round 8
// 307.838 us; speedup vs baseline: 1.2693x; 1.0934x over previous
//
#include <hip/hip_runtime.h>
#include <hip/hip_bf16.h>

#define L_SZ 1024
#define P_SZ 2048
#define HID 256
#define NH 8
#define HD 32
#define NRBF 50
#define CH 32
#define NCH 64

typedef unsigned int uint32;
typedef _Float16 half2_t __attribute__((ext_vector_type(2)));
typedef __fp16 fp16x2_t __attribute__((ext_vector_type(2)));

__constant__ float kINV_SCALE = 0.17677669529663687f; // 1/sqrt(32)

static __device__ __forceinline__ unsigned short f2h(float f) {
    union { _Float16 h; unsigned short u; } x; x.h = (_Float16)f; return x.u;
}
static __device__ __forceinline__ float h2f(unsigned short u) {
    union { unsigned short u; _Float16 h; } x; x.u = u; return (float)x.h;
}
static __device__ __forceinline__ half2_t u2h2(uint32 u) {
    union { uint32 u; half2_t h; } x; x.u = u; return x.h;
}
static __device__ __forceinline__ half2_t pk2h(float a, float b) {
    union { fp16x2_t p; half2_t h; } x; x.p = __builtin_amdgcn_cvt_pkrtz(a, b); return x.h;
}

// async global->LDS, 16B per lane. LDS dest = wave-uniform base + lane*16.
static __device__ __forceinline__ void g2l16(const void* g, void* l) {
    __builtin_amdgcn_global_load_lds(
        (__attribute__((address_space(1))) void*)(void*)g,
        (__attribute__((address_space(3))) void*)l, 16, 0, 0);
}
static __device__ __forceinline__ void g2l4(const void* g, void* l) {
    __builtin_amdgcn_global_load_lds(
        (__attribute__((address_space(1))) void*)(void*)g,
        (__attribute__((address_space(3))) void*)l, 4, 0, 0);
}

#define WAITV0 asm volatile("s_waitcnt vmcnt(0)" ::: "memory")
#define CFENCE asm volatile("" ::: "memory")

// ---------------------------------------------------------------------------
// Kernel 1: Q = lig@Wq+bq (f32), K = prot@Wk+bk (f16), V = prot@Wv+bv (f16)
// ---------------------------------------------------------------------------
__global__ __launch_bounds__(64) void k_proj(
    const float* __restrict__ lig, const float* __restrict__ prot,
    const float* __restrict__ Wq, const float* __restrict__ bq,
    const float* __restrict__ Wk, const float* __restrict__ bk,
    const float* __restrict__ Wv, const float* __restrict__ bv,
    float* __restrict__ Qf, unsigned short* __restrict__ Kb,
    unsigned short* __restrict__ Vb)
{
    __shared__ float As[8 * HID];
    const int t = threadIdx.x;
    const int r0 = blockIdx.x * 8;

    const float* src; const float* W; const float* bias; int mode; int row0;
    if (r0 < L_SZ)            { src = lig  + (size_t)r0 * HID;               W = Wq; bias = bq; mode = 0; row0 = r0; }
    else if (r0 < L_SZ + P_SZ){ src = prot + (size_t)(r0 - L_SZ) * HID;      W = Wk; bias = bk; mode = 1; row0 = r0 - L_SZ; }
    else                      { src = prot + (size_t)(r0 - L_SZ - P_SZ)*HID; W = Wv; bias = bv; mode = 2; row0 = r0 - L_SZ - P_SZ; }

    float4* A4 = (float4*)As;
    const float4* S4 = (const float4*)src;
    #pragma unroll
    for (int j = 0; j < 8; ++j) A4[t + j * 64] = S4[t + j * 64];
    __syncthreads();

    float acc[8][4];
    #pragma unroll
    for (int r = 0; r < 8; ++r)
        #pragma unroll
        for (int c = 0; c < 4; ++c) acc[r][c] = 0.f;

    for (int k4 = 0; k4 < 64; ++k4) {
        float4 av[8];
        #pragma unroll
        for (int r = 0; r < 8; ++r) av[r] = A4[r * 64 + k4];
        #pragma unroll
        for (int kk = 0; kk < 4; ++kk) {
            const float* wr = W + (size_t)(k4 * 4 + kk) * HID + t;
            #pragma unroll
            for (int c = 0; c < 4; ++c) {
                float wv = wr[c * 64];
                #pragma unroll
                for (int r = 0; r < 8; ++r)
                    acc[r][c] += ((const float*)&av[r])[kk] * wv;
            }
        }
    }

    #pragma unroll
    for (int c = 0; c < 4; ++c) {
        const int col = t + c * 64;
        const float bb = bias[col];
        #pragma unroll
        for (int r = 0; r < 8; ++r) {
            float v = acc[r][c] + bb;
            size_t idx = (size_t)(row0 + r) * HID + col;
            if (mode == 0)      Qf[idx] = v;
            else if (mode == 1) Kb[idx] = f2h(v);
            else                Vb[idx] = f2h(v);
        }
    }
}

// ---------------------------------------------------------------------------
// Kernel 2: fused bias + QK^T + softmax + weights + PV.
// One block per ligand row, 256 threads, 2 blocks/CU.
// Wait-before-use async pipeline: each iter begins with vmcnt(0)+s_barrier
// (chunk c visible, all waves past compute(c-1)), THEN issues stage(c+1),
// THEN computes chunk c — prefetch gets a full iteration of slack.
// LDS (R5 layout, known-good banking): kv dbuf 2x16384 @0 |
//   rbf dbuf 2x6400 @32768 (linear 200B rows) | slg f16 [2048][8]
//   dword-swizzled @45568 | red[16] @78336. Total 78400 B.
// ---------------------------------------------------------------------------
__global__ __launch_bounds__(256, 2) void k_attn(
    const float* __restrict__ rbf, const float* __restrict__ Qf,
    const unsigned short* __restrict__ Kb, const unsigned short* __restrict__ Vb,
    const float* __restrict__ Wrbf, const float* __restrict__ brbf,
    float* __restrict__ attn_out, float* __restrict__ att_ws)
{
    __shared__ __align__(16) char sm[78400];
    char* rbfB = sm + 32768;
    char* slgB = sm + 45568;
    float* red = (float*)(sm + 78336);

    const int t = threadIdx.x;
    const int lane = t & 63;
    const int wv = t >> 6;
    const int r = t & 31;     // protein row within chunk
    const int h = t >> 5;     // head 0..7
    const int l = blockIdx.x;

    // stage one 32-row K or V chunk (16 KB), XOR-swizzled via pre-swizzled
    // global source (LDS dest stays linear). 4 loads per wave.
    auto stageKV = [&](const unsigned short* src, int c, char* dst) {
        const char* gb = (const char*)src + (size_t)c * (CH * 512);
        #pragma unroll
        for (int k = 0; k < 4; ++k) {
            int s = wv * 4 + k;               // 1KB slab 0..15
            int row = s * 2 + (lane >> 5);
            int off = ((lane & 31) ^ (row & 31)) << 4;
            g2l16(gb + row * 512 + off, dst + s * 1024);
        }
    };
    // stage one 32-row rbf chunk (6400 B), linear rows at r*200
    auto stageRBF = [&](int c, char* dst) {
        const char* gb = (const char*)rbf + (size_t)l * 409600 + (size_t)c * 6400;
        g2l16(gb + wv * 1024 + (lane << 4), dst + wv * 1024);
        if (wv == 0)      g2l16(gb + 4096 + (lane << 4), dst + 4096);
        else if (wv == 1) g2l16(gb + 5120 + (lane << 4), dst + 5120);
        else if (wv == 2) g2l4 (gb + 6144 + (lane << 2), dst + 6144);
    };

    // ---- per-thread preloads: Wrbf column h (25 half2), Q head h (16 half2)
    half2_t wrb[25];
    #pragma unroll
    for (int j = 0; j < 25; ++j)
        wrb[j] = pk2h(Wrbf[(2 * j) * NH + h], Wrbf[(2 * j + 1) * NH + h]);
    const float bh = brbf[h];

    half2_t qp[16];
    {
        const float* qq = Qf + (size_t)l * HID + h * HD;
        #pragma unroll
        for (int n = 0; n < 16; ++n)
            qp[n] = pk2h(qq[2 * n], qq[2 * n + 1]);
    }

    // slg address swizzle: dword d of row p stored at d ^ ((p>>3)&3).
    const int doff = ((((h >> 1) ^ ((r >> 3) & 3)) << 2) | ((h & 1) << 1));

    // ================= Pass 1: logits + running max =========================
    stageKV(Kb, 0, sm);
    stageRBF(0, rbfB);

    float mx = -3.0e38f;
    for (int c = 0; c < NCH; ++c) {
        WAITV0;                              // own chunk-c loads done
        __builtin_amdgcn_s_barrier();        // everyone's done; buf^1 free
        CFENCE;
        const int cb = c & 1;
        char* kb = sm + cb * 16384;
        char* rb = rbfB + cb * 6400;
        if (c + 1 < NCH) {                   // prefetch with a full iter of slack
            stageKV(Kb, c + 1, sm + (cb ^ 1) * 16384);
            stageRBF(c + 1, rbfB + (cb ^ 1) * 6400);
        }
        // bias = brbf[h] + rbf[l, p, :] . Wrbf[:, h]   (dual chains)
        float b0 = bh, b1 = 0.f;
        const char* rrow = rb + r * 200;
        #pragma unroll
        for (int j = 0; j < 12; ++j) {
            float2 v0 = *(const float2*)(rrow + (2 * j) * 8);
            float2 v1 = *(const float2*)(rrow + (2 * j + 1) * 8);
            b0 = __builtin_amdgcn_fdot2(pk2h(v0.x, v0.y), wrb[2 * j], b0, false);
            b1 = __builtin_amdgcn_fdot2(pk2h(v1.x, v1.y), wrb[2 * j + 1], b1, false);
        }
        {
            float2 v = *(const float2*)(rrow + 24 * 8);
            b0 = __builtin_amdgcn_fdot2(pk2h(v.x, v.y), wrb[24], b0, false);
        }
        // qk = Q[l,h,:] . K[p,h,:]   (dual chains)
        float qk0 = 0.f, qk1 = 0.f;
        const char* krow = kb + r * 512;
        #pragma unroll
        for (int jw = 0; jw < 2; ++jw) {
            int offA = (h * 64 + jw * 16) ^ (r << 4);
            int offB = (h * 64 + (jw + 2) * 16) ^ (r << 4);
            uint4 ka = *(const uint4*)(krow + offA);
            uint4 kbv = *(const uint4*)(krow + offB);
            qk0 = __builtin_amdgcn_fdot2(u2h2(ka.x),  qp[jw * 4 + 0], qk0, false);
            qk1 = __builtin_amdgcn_fdot2(u2h2(kbv.x), qp[(jw + 2) * 4 + 0], qk1, false);
            qk0 = __builtin_amdgcn_fdot2(u2h2(ka.y),  qp[jw * 4 + 1], qk0, false);
            qk1 = __builtin_amdgcn_fdot2(u2h2(kbv.y), qp[(jw + 2) * 4 + 1], qk1, false);
            qk0 = __builtin_amdgcn_fdot2(u2h2(ka.z),  qp[jw * 4 + 2], qk0, false);
            qk1 = __builtin_amdgcn_fdot2(u2h2(kbv.z), qp[(jw + 2) * 4 + 2], qk1, false);
            qk0 = __builtin_amdgcn_fdot2(u2h2(ka.w),  qp[jw * 4 + 3], qk0, false);
            qk1 = __builtin_amdgcn_fdot2(u2h2(kbv.w), qp[(jw + 2) * 4 + 3], qk1, false);
        }
        float lg = (qk0 + qk1) * kINV_SCALE + (b0 + b1);
        mx = fmaxf(mx, lg);
        *(unsigned short*)(slgB + (size_t)((c * CH + r) * 16) + doff) = f2h(lg);
    }

    // ---- softmax stats: half-wave butterflies (32 lanes own head h) ----
    #pragma unroll
    for (int msk = 1; msk <= 16; msk <<= 1) mx = fmaxf(mx, __shfl_xor(mx, msk));
    float sme = 0.f;
    for (int c = 0; c < NCH; ++c) {
        unsigned short u = *(const unsigned short*)(slgB + (size_t)((c * CH + r) * 16) + doff);
        sme += __expf(h2f(u) - mx);
    }
    #pragma unroll
    for (int msk = 1; msk <= 16; msk <<= 1) sme += __shfl_xor(sme, msk);
    if ((t & 31) == 0) { red[h * 2] = mx; red[h * 2 + 1] = 1.f / sme; }

    stageKV(Vb, 0, sm);          // V chunk 0 overlaps pass-2 compute
    __syncthreads();             // pass boundary (publishes red + slg)

    // ================= Pass 2: normalized weights ===========================
    {
        float mh[8], ih[8];
        #pragma unroll
        for (int hh = 0; hh < 8; ++hh) { mh[hh] = red[hh * 2]; ih[hh] = red[hh * 2 + 1]; }
        const int sel = t & 1;                       // 0: heads 0-3, 1: heads 4-7
        float m0 = sel ? mh[4] : mh[0], i0 = sel ? ih[4] : ih[0];
        float m1 = sel ? mh[5] : mh[1], i1 = sel ? ih[5] : ih[1];
        float m2 = sel ? mh[6] : mh[2], i2 = sel ? ih[6] : ih[2];
        float m3 = sel ? mh[7] : mh[3], i3 = sel ? ih[7] : ih[3];
        const int x = (t >> 4) & 3;                  // (p>>3)&3, const per thread
        const int dA = (((2 * sel)     ^ x) << 2);
        const int dB = (((2 * sel + 1) ^ x) << 2);
        float4* ao = (float4*)(attn_out + (size_t)l * (P_SZ * NH));
        #pragma unroll
        for (int n = 0; n < 16; ++n) {
            int f = t + n * 256;
            int p = (t >> 1) + n * 128;
            char* rowp = slgB + p * 16;
            uint32 a = *(uint32*)(rowp + dA);
            uint32 b = *(uint32*)(rowp + dB);
            float w0 = __expf(h2f((unsigned short)(a & 0xffffu)) - m0) * i0;
            float w1 = __expf(h2f((unsigned short)(a >> 16))     - m1) * i1;
            float w2 = __expf(h2f((unsigned short)(b & 0xffffu)) - m2) * i2;
            float w3 = __expf(h2f((unsigned short)(b >> 16))     - m3) * i3;
            ao[f] = make_float4(w0, w1, w2, w3);
            *(uint32*)(rowp + dA) = (uint32)f2h(w0) | ((uint32)f2h(w1) << 16);
            *(uint32*)(rowp + dB) = (uint32)f2h(w2) | ((uint32)f2h(w3) << 16);
        }
    }
    __syncthreads();             // pass boundary (slg weights visible; V0 arrived)

    // ================= Pass 3: PV with double-buffered V =====================
    {
        const int h3 = t >> 5;        // head
        const int dq = (t >> 3) & 3;  // dim quad (8 dims)
        const int ps = t & 7;         // p slice
        const int vinner = h3 * 64 + dq * 16;
        float acc[8] = {0.f, 0.f, 0.f, 0.f, 0.f, 0.f, 0.f, 0.f};
        for (int c = 0; c < NCH; ++c) {
            WAITV0;
            __builtin_amdgcn_s_barrier();
            CFENCE;
            const int cb = c & 1;
            char* vb = sm + cb * 16384;
            if (c + 1 < NCH) stageKV(Vb, c + 1, sm + (cb ^ 1) * 16384);
            #pragma unroll
            for (int m = 0; m < 4; ++m) {
                int rr = m * 8 + ps;
                int p = c * CH + rr;
                int dw = (((h3 >> 1) ^ m) << 2) | ((h3 & 1) << 1);
                float w = h2f(*(const unsigned short*)(slgB + p * 16 + dw));
                int off = vinner ^ (rr << 4);
                uint4 vvv = *(const uint4*)(vb + rr * 512 + off);
                half2_t x0 = u2h2(vvv.x), x1 = u2h2(vvv.y), x2 = u2h2(vvv.z), x3 = u2h2(vvv.w);
                acc[0] += w * (float)x0.x; acc[1] += w * (float)x0.y;
                acc[2] += w * (float)x1.x; acc[3] += w * (float)x1.y;
                acc[4] += w * (float)x2.x; acc[5] += w * (float)x2.y;
                acc[6] += w * (float)x3.x; acc[7] += w * (float)x3.y;
            }
        }
        #pragma unroll
        for (int d = 0; d < 8; ++d) {
            acc[d] += __shfl_xor(acc[d], 1);
            acc[d] += __shfl_xor(acc[d], 2);
            acc[d] += __shfl_xor(acc[d], 4);
        }
        if (ps == 0) {
            float* dst = att_ws + (size_t)l * HID + h3 * HD + dq * 8;
            *(float4*)dst       = make_float4(acc[0], acc[1], acc[2], acc[3]);
            *(float4*)(dst + 4) = make_float4(acc[4], acc[5], acc[6], acc[7]);
        }
    }
}

// ---------------------------------------------------------------------------
// Kernel 3: y = lig + attended@Wo + bo; LayerNorm
// ---------------------------------------------------------------------------
__global__ __launch_bounds__(256) void k_out(
    const float* __restrict__ att, const float* __restrict__ lig,
    const float* __restrict__ Wo, const float* __restrict__ bo,
    const float* __restrict__ gamma, const float* __restrict__ beta,
    float* __restrict__ out)
{
    __shared__ float a[HID];
    __shared__ float red[8];
    const int l = blockIdx.x, t = threadIdx.x;
    if (t < 64) ((float4*)a)[t] = ((const float4*)(att + (size_t)l * HID))[t];
    __syncthreads();

    float acc = bo[t];
    for (int k4 = 0; k4 < 64; ++k4) {
        float4 av = ((float4*)a)[k4];
        const float* wr = Wo + (size_t)(k4 * 4) * HID + t;
        acc += av.x * wr[0];
        acc += av.y * wr[HID];
        acc += av.z * wr[2 * HID];
        acc += av.w * wr[3 * HID];
    }
    float y = lig[(size_t)l * HID + t] + acc;

    float s = y, sq = y * y;
    #pragma unroll
    for (int msk = 1; msk < 64; msk <<= 1) {
        s  += __shfl_xor(s, msk);
        sq += __shfl_xor(sq, msk);
    }
    const int lane = t & 63, wvi = t >> 6;
    if (lane == 0) { red[wvi * 2] = s; red[wvi * 2 + 1] = sq; }
    __syncthreads();
    float ts = red[0] + red[2] + red[4] + red[6];
    float tq = red[1] + red[3] + red[5] + red[7];
    float mu = ts * (1.0f / HID);
    float var = tq * (1.0f / HID) - mu * mu;
    out[(size_t)l * HID + t] = (y - mu) * rsqrtf(var + 1e-5f) * gamma[t] + beta[t];
}

// ---------------------------------------------------------------------------
extern "C" void kernel_launch(void* const* d_in, const int* in_sizes, int n_in,
                              void* d_out, int out_size, void* d_ws, size_t ws_size,
                              hipStream_t stream)
{
    (void)in_sizes; (void)n_in; (void)out_size; (void)ws_size;

    const float* lig   = (const float*)d_in[0];
    const float* prot  = (const float*)d_in[1];
    const float* rbf   = (const float*)d_in[2];
    const float* Wq    = (const float*)d_in[5];
    const float* bq    = (const float*)d_in[6];
    const float* Wk    = (const float*)d_in[7];
    const float* bk    = (const float*)d_in[8];
    const float* Wv    = (const float*)d_in[9];
    const float* bv    = (const float*)d_in[10];
    const float* Wrbf  = (const float*)d_in[11];
    const float* brbf  = (const float*)d_in[12];
    const float* Wo    = (const float*)d_in[13];
    const float* bo    = (const float*)d_in[14];
    const float* gamma = (const float*)d_in[15];
    const float* beta  = (const float*)d_in[16];

    float* out0 = (float*)d_out;                          // [1024,256]
    float* attn = (float*)d_out + (size_t)L_SZ * HID;     // [1024,2048,8]

    char* ws = (char*)d_ws;
    float*          Qf     = (float*)ws;                          // 1 MB
    unsigned short* Kb     = (unsigned short*)(ws + (1u << 20));  // 1 MB
    unsigned short* Vb     = (unsigned short*)(ws + (2u << 20));  // 1 MB
    float*          att_ws = (float*)(ws + (3u << 20));           // 1 MB

    hipLaunchKernelGGL(k_proj, dim3((L_SZ + 2 * P_SZ) / 8), dim3(64), 0, stream,
                       lig, prot, Wq, bq, Wk, bk, Wv, bv, Qf, Kb, Vb);
    hipLaunchKernelGGL(k_attn, dim3(L_SZ), dim3(256), 0, stream,
                       rbf, Qf, Kb, Vb, Wrbf, brbf, attn, att_ws);
    hipLaunchKernelGGL(k_out, dim3(L_SZ), dim3(256), 0, stream,
                       att_ws, lig, Wo, bo, gamma, beta, out0);
}